// Round 1
// baseline (267.025 us; speedup 1.0000x reference)
//
#include <hip/hip_runtime.h>
#include <math.h>

#define BB   4
#define CINN 32
#define COUTT 32
#define HH   64
#define WW2  64
#define KCL  32
#define MM   16
#define AREA 9
#define SS   4096
#define FF   288
#define NBLK 32      // assign blocks per batch
#define PPB  128     // points per assign block (== blockDim)
#define KMIT 10

// ---------------- feat: 3x3 box mean of x -> feat[b][s][c] ----------------
__global__ void feat_kernel(const float* __restrict__ x, float* __restrict__ feat) {
    int blk = blockIdx.x;                 // B*16 blocks
    int b = blk >> 4;
    int s = ((blk & 15) << 8) + threadIdx.x;
    int h = s >> 6, w = s & 63;
    const float* xb = x + (size_t)(b * CINN) * SS;
    float* fo = feat + ((size_t)b * SS + s) * CINN;
    for (int c = 0; c < CINN; ++c) {
        const float* xp = xb + c * SS + (h << 6) + w;
        float sum = 0.f;
        #pragma unroll
        for (int i = 0; i < 3; ++i) {
            int hh = h + i - 1;
            bool okh = (hh >= 0) && (hh < HH);
            #pragma unroll
            for (int j = 0; j < 3; ++j) {
                int ww = w + j - 1;
                bool ok = okh && (ww >= 0) && (ww < WW2);
                float v = ok ? xp[(i - 1) * WW2 + (j - 1)] : 0.f;
                sum += v;
            }
        }
        fo[c] = sum / 9.0f;
    }
}

// ---------------- centroid init: strided linspace indices ----------------
__global__ void init_cent_kernel(const float* __restrict__ feat, float* __restrict__ cent) {
    int b = blockIdx.x;
    int t = threadIdx.x;                  // 1024 threads = K*CIN
    int k = t >> 5, c = t & 31;
    int s0 = (int)((double)k * 4095.0 / 31.0);
    cent[((size_t)b * KCL + k) * CINN + c] = feat[((size_t)b * SS + s0) * CINN + c];
}

// ---------------- assign (+ optional partial sums) ----------------
template <bool PARTIALS, bool WRITE_IDX>
__global__ __launch_bounds__(PPB) void assign_kernel(
        const float* __restrict__ feat, const float* __restrict__ cent,
        int* __restrict__ idx, float* __restrict__ psums, float* __restrict__ pcnts) {
    __shared__ float cl[KCL * CINN];        // 4 KB
    __shared__ float sums[2][KCL * 33];     // padded: bank = (k+c)%32
    __shared__ float wcnt[2][KCL];
    int blk = blockIdx.x;
    int b = blk >> 5;                       // NBLK = 32
    int nb = blk & 31;
    int tid = threadIdx.x;                  // 128

    for (int i = tid; i < KCL * CINN; i += PPB) cl[i] = cent[(size_t)b * KCL * CINN + i];
    if (PARTIALS) {
        for (int i = tid; i < 2 * KCL * 33; i += PPB) (&sums[0][0])[i] = 0.f;
    }
    __syncthreads();

    int s = nb * PPB + tid;
    float p[CINN];
    const float* fp = feat + ((size_t)b * SS + s) * CINN;
    #pragma unroll
    for (int c4 = 0; c4 < 8; ++c4) {
        float4 v = reinterpret_cast<const float4*>(fp)[c4];
        p[c4 * 4 + 0] = v.x; p[c4 * 4 + 1] = v.y;
        p[c4 * 4 + 2] = v.z; p[c4 * 4 + 3] = v.w;
    }
    float dmin = 3.4e38f; int kmin = 0;
    for (int k = 0; k < KCL; ++k) {
        float d = 0.f;
        #pragma unroll
        for (int c = 0; c < CINN; ++c) {
            float diff = p[c] - cl[k * CINN + c];
            d += diff * diff;
        }
        if (d < dmin) { dmin = d; kmin = k; }   // strict < : first-min wins (matches argmin)
    }
    if (WRITE_IDX) idx[(size_t)b * SS + s] = kmin;

    if (PARTIALS) {
        int lane = tid & 63, wid = tid >> 6;
        // per-wave counts via ballot (deterministic)
        float myCnt = 0.f;
        for (int k = 0; k < KCL; ++k) {
            unsigned long long m = __ballot(kmin == k);
            if (lane == k) myCnt = (float)__popcll(m);
        }
        if (lane < KCL) wcnt[wid][lane] = myCnt;
        // per-wave private LDS scatter (padded stride 33: distinct k -> distinct banks)
        #pragma unroll
        for (int c = 0; c < CINN; ++c)
            atomicAdd(&sums[wid][kmin * 33 + c], p[c]);
        __syncthreads();
        for (int pair = tid; pair < KCL * CINN; pair += PPB) {
            int k = pair >> 5, c = pair & 31;
            psums[(((size_t)b * NBLK + nb) * KCL + k) * CINN + c] =
                sums[0][k * 33 + c] + sums[1][k * 33 + c];
        }
        if (tid < KCL) pcnts[((size_t)b * NBLK + nb) * KCL + tid] = wcnt[0][tid] + wcnt[1][tid];
    }
}

// ---------------- centroid update (fixed-order reduction over blocks) ----------------
__global__ void update_cent_kernel(const float* __restrict__ psums, const float* __restrict__ pcnts,
                                   float* __restrict__ cent) {
    int b = blockIdx.x;
    int t = threadIdx.x;                   // 1024 = K*CIN
    int k = t >> 5, c = t & 31;
    float sum = 0.f, cnt = 0.f;
    for (int nb = 0; nb < NBLK; ++nb) {
        sum += psums[(((size_t)b * NBLK + nb) * KCL + k) * CINN + c];
        cnt += pcnts[((size_t)b * NBLK + nb) * KCL + k];
    }
    if (cnt > 0.f) cent[((size_t)b * KCL + k) * CINN + c] = sum / fmaxf(cnt, 1.0f);
    // else: keep previous centroid (matches jnp.where)
}

// ---------------- per-cluster MLP heads ----------------
__global__ void mlp_kernel(const float* __restrict__ cent,
                           const float* __restrict__ kh_w1, const float* __restrict__ kh_b1,
                           const float* __restrict__ kh_w2, const float* __restrict__ kh_b2,
                           const float* __restrict__ area_w, const float* __restrict__ area_b,
                           const float* __restrict__ cin_w, const float* __restrict__ cin_b,
                           const float* __restrict__ cout_w, const float* __restrict__ cout_b,
                           const float* __restrict__ bh_w1, const float* __restrict__ bh_b1,
                           const float* __restrict__ bh_w2, const float* __restrict__ bh_b2,
                           const float* __restrict__ bh_w3, const float* __restrict__ bh_b3,
                           float* __restrict__ wprod, float* __restrict__ wcoutA,
                           float* __restrict__ biasA) {
    __shared__ float cl[CINN], f1[MM], f2[MM], g1[MM], g2[MM], wc[CINN], wa[AREA];
    int bk = blockIdx.x;                   // b*K + k
    int lane = threadIdx.x;                // 64
    if (lane < CINN) cl[lane] = cent[(size_t)bk * CINN + lane];
    __syncthreads();
    if (lane < MM) {
        float a = kh_b1[lane], a2 = bh_b1[lane];
        for (int c = 0; c < CINN; ++c) {
            a  += cl[c] * kh_w1[c * MM + lane];
            a2 += cl[c] * bh_w1[c * MM + lane];
        }
        f1[lane] = fmaxf(a, 0.f); g1[lane] = fmaxf(a2, 0.f);
    }
    __syncthreads();
    if (lane < MM) {
        float a = kh_b2[lane], a2 = bh_b2[lane];
        for (int m = 0; m < MM; ++m) {
            a  += f1[m] * kh_w2[m * MM + lane];
            a2 += g1[m] * bh_w2[m * MM + lane];
        }
        f2[lane] = fmaxf(a, 0.f); g2[lane] = fmaxf(a2, 0.f);
    }
    __syncthreads();
    if (lane < CINN) {
        float ac = cin_b[lane], ao = cout_b[lane], ab = bh_b3[lane];
        for (int m = 0; m < MM; ++m) {
            ac += f2[m] * cin_w[m * CINN + lane];
            ao += f2[m] * cout_w[m * COUTT + lane];
            ab += g2[m] * bh_w3[m * COUTT + lane];
        }
        wc[lane] = 1.f / (1.f + expf(-ac));
        wcoutA[(size_t)bk * COUTT + lane] = 1.f / (1.f + expf(-ao));
        biasA[(size_t)bk * COUTT + lane] = ab;
    }
    if (lane < AREA) {
        float aa = area_b[lane];
        for (int m = 0; m < MM; ++m) aa += f2[m] * area_w[m * AREA + lane];
        wa[lane] = 1.f / (1.f + expf(-aa));
    }
    __syncthreads();
    for (int f = lane; f < FF; f += 64)
        wprod[(size_t)bk * FF + f] = wc[f / 9] * wa[f % 9];
}

// ---------------- main factorized conv ----------------
__global__ __launch_bounds__(256) void conv_kernel(
        const float* __restrict__ x, const int* __restrict__ idx,
        const float* __restrict__ wprod, const float* __restrict__ wcoutA,
        const float* __restrict__ biasA, const float* __restrict__ base,
        float* __restrict__ out) {
    __shared__ float bl[FF * COUTT];       // 36.9 KB
    int blk = blockIdx.x;                  // B*128
    int b = blk >> 7;
    int s0 = (blk & 127) << 5;             // 32 points per block
    int tid = threadIdx.x;
    for (int i = tid; i < FF * COUTT; i += 256) bl[i] = base[i];
    __syncthreads();
    int co4 = (tid & 7) << 2;              // 4 consecutive cout per thread
    int s = s0 + (tid >> 3);
    int h = s >> 6, w = s & 63;
    int k = idx[(size_t)b * SS + s];
    const float* wp = wprod + ((size_t)b * KCL + k) * FF;
    const float* xb = x + ((size_t)(b * CINN) << 12) + (h << 6) + w;
    bool vh0 = h > 0, vh2 = h < 63, vw0 = w > 0, vw2 = w < 63;
    bool va[9] = { vh0 && vw0, vh0, vh0 && vw2,
                   vw0,        true, vw2,
                   vh2 && vw0, vh2, vh2 && vw2 };
    const int offA[9] = { -65, -64, -63, -1, 0, 1, 63, 64, 65 };
    float ax = 0.f, ay = 0.f, az = 0.f, aw = 0.f;
    int f = 0;
    for (int c = 0; c < CINN; ++c) {
        const float* xp = xb + (c << 12);
        #pragma unroll
        for (int a = 0; a < 9; ++a) {
            float val = va[a] ? xp[offA[a]] : 0.f;
            float q = val * wp[f];
            float4 bb = *reinterpret_cast<const float4*>(&bl[(f << 5) + co4]);
            ax += q * bb.x; ay += q * bb.y; az += q * bb.z; aw += q * bb.w;
            ++f;
        }
    }
    const float* wo = wcoutA + ((size_t)b * KCL + k) * COUTT + co4;
    const float* bo = biasA + ((size_t)b * KCL + k) * COUTT + co4;
    float* op = out + ((size_t)(b * COUTT + co4) << 12) + s;
    op[0]     = wo[0] * ax + bo[0];
    op[4096]  = wo[1] * ay + bo[1];
    op[8192]  = wo[2] * az + bo[2];
    op[12288] = wo[3] * aw + bo[3];
}

extern "C" void kernel_launch(void* const* d_in, const int* in_sizes, int n_in,
                              void* d_out, int out_size, void* d_ws, size_t ws_size,
                              hipStream_t stream) {
    (void)in_sizes; (void)n_in; (void)out_size; (void)ws_size;
    const float* x      = (const float*)d_in[0];
    const float* kh_w1  = (const float*)d_in[1];
    const float* kh_b1  = (const float*)d_in[2];
    const float* kh_w2  = (const float*)d_in[3];
    const float* kh_b2  = (const float*)d_in[4];
    const float* area_w = (const float*)d_in[5];
    const float* area_b = (const float*)d_in[6];
    const float* cin_w  = (const float*)d_in[7];
    const float* cin_b  = (const float*)d_in[8];
    const float* cout_w = (const float*)d_in[9];
    const float* cout_b = (const float*)d_in[10];
    const float* base   = (const float*)d_in[11];
    const float* bh_w1  = (const float*)d_in[12];
    const float* bh_b1  = (const float*)d_in[13];
    const float* bh_w2  = (const float*)d_in[14];
    const float* bh_b2  = (const float*)d_in[15];
    const float* bh_w3  = (const float*)d_in[16];
    const float* bh_b3  = (const float*)d_in[17];
    float* out = (float*)d_out;

    float* ws    = (float*)d_ws;
    float* feat  = ws;                             // B*S*CIN     = 524288
    float* cent  = feat + (size_t)BB * SS * CINN;  // B*K*CIN     = 4096
    int*   idx   = (int*)(cent + BB * KCL * CINN); // B*S         = 16384
    float* psums = (float*)(idx + BB * SS);        // B*NB*K*CIN  = 131072
    float* pcnts = psums + (size_t)BB * NBLK * KCL * CINN; // B*NB*K = 4096
    float* wprod = pcnts + BB * NBLK * KCL;        // B*K*F       = 36864
    float* wco   = wprod + (size_t)BB * KCL * FF;  // B*K*COUT    = 4096
    float* bia   = wco + BB * KCL * COUTT;         // B*K*COUT    = 4096

    feat_kernel<<<BB * 16, 256, 0, stream>>>(x, feat);
    init_cent_kernel<<<BB, 1024, 0, stream>>>(feat, cent);
    for (int it = 0; it < KMIT; ++it) {
        assign_kernel<true, false><<<BB * NBLK, PPB, 0, stream>>>(feat, cent, idx, psums, pcnts);
        update_cent_kernel<<<BB, 1024, 0, stream>>>(psums, pcnts, cent);
    }
    assign_kernel<false, true><<<BB * NBLK, PPB, 0, stream>>>(feat, cent, idx, psums, pcnts);
    mlp_kernel<<<BB * KCL, 64, 0, stream>>>(cent, kh_w1, kh_b1, kh_w2, kh_b2,
                                            area_w, area_b, cin_w, cin_b, cout_w, cout_b,
                                            bh_w1, bh_b1, bh_w2, bh_b2, bh_w3, bh_b3,
                                            wprod, wco, bia);
    conv_kernel<<<BB * 128, 256, 0, stream>>>(x, idx, wprod, wco, bia, base, out);
}